// Round 1
// baseline (363.758 us; speedup 1.0000x reference)
//
#include <hip/hip_runtime.h>
#include <hip/hip_bf16.h>

#define NN 20000        // N_NODES
#define NE 640000       // N_EDGES
#define FEAT 416

// d_ws layout: int flag at byte 0 (1 = int32 layout, 2 = int64 layout),
// bb5 floats (NN*15) starting at byte 64.

__global__ __launch_bounds__(256) void prep_kernel(const float* __restrict__ bb,
                                                   const int* __restrict__ ei,
                                                   int* __restrict__ flag,
                                                   float* __restrict__ bb5) {
    int t = blockIdx.x * 256 + threadIdx.x;

    // dtype probe: if edge_index is int64, the high dword of each qword is 0
    // (values are in [0, 20000)). With int32 data these dwords are random
    // indices, P(all 64 == 0) ~ (1/20000)^64 ~ 0.
    if (blockIdx.x == 0 && threadIdx.x < 64) {
        int v = ei[2 * threadIdx.x + 1];
        unsigned long long m = __ballot(v != 0);
        if (threadIdx.x == 0) flag[0] = (m == 0ULL) ? 2 : 1;
    }

    if (t < NN) {
        const float* r = bb + (size_t)t * 12;
        float Nx = r[0], Ny = r[1], Nz = r[2];
        float CAx = r[3], CAy = r[4], CAz = r[5];
        float Cx = r[6], Cy = r[7], Cz = r[8];
        float Ox = r[9], Oy = r[10], Oz = r[11];
        float bx = CAx - Nx, by = CAy - Ny, bz = CAz - Nz;
        float cx = Cx - CAx, cy = Cy - CAy, cz = Cz - CAz;
        float ax = by * cz - bz * cy;
        float ay = bz * cx - bx * cz;
        float az = bx * cy - by * cx;
        float vx = -0.58273431f * ax + 0.56802827f * bx - 0.54067466f * cx + CAx;
        float vy = -0.58273431f * ay + 0.56802827f * by - 0.54067466f * cy + CAy;
        float vz = -0.58273431f * az + 0.56802827f * bz - 0.54067466f * cz + CAz;
        float* w = bb5 + (size_t)t * 15;
        w[0] = Nx;  w[1] = Ny;  w[2] = Nz;
        w[3] = CAx; w[4] = CAy; w[5] = CAz;
        w[6] = Cx;  w[7] = Cy;  w[8] = Cz;
        w[9] = Ox;  w[10] = Oy; w[11] = Oz;
        w[12] = vx; w[13] = vy; w[14] = vz;
    }
}

#define RBF_BLOCKS 62500   // NE*25/256
#define POS_BLOCKS 40000   // NE*16/256

__device__ __forceinline__ void load_idx(const int* __restrict__ ei, int sel, int e,
                                         int& dst, int& src) {
    if (sel == 2) {            // int64 layout: low dword of qword
        dst = ei[2 * e];
        src = ei[2 * (NE + e)];
    } else {                   // int32 layout
        dst = ei[e];
        src = ei[NE + e];
    }
}

__global__ __launch_bounds__(256) void edge_kernel(const int* __restrict__ ei,
                                                   const float* __restrict__ bb5,
                                                   const int* __restrict__ flag,
                                                   float* __restrict__ out) {
    const int sel = flag[0];

    if (blockIdx.x < RBF_BLOCKS) {
        int t = blockIdx.x * 256 + threadIdx.x;       // < NE*25 exactly
        int e = t / 25;
        int p = t - e * 25;                           // pair index: i*5 + j
        int i = p / 5;                                // src atom
        int j = p - i * 5;                            // dst atom
        int dst, src;
        load_idx(ei, sel, e, dst, src);
        const float* S = bb5 + src * 15 + i * 3;
        const float* D = bb5 + dst * 15 + j * 3;
        float dx = S[0] - D[0] + 1e-8f;
        float dy = S[1] - D[1] + 1e-8f;
        float dz = S[2] - D[2] + 1e-8f;
        float dist = sqrtf(dx * dx + dy * dy + dz * dz);
        // (dist - mu_k)/sigma = dist*0.8 - mu_k*0.8 ; mu_k = k*20/15, sigma=1.25
        float a = dist * 0.8f;
        float* o = out + (size_t)e * FEAT + p * 16;
#pragma unroll
        for (int g = 0; g < 4; ++g) {
            float4 r;
            float u;
            u = a - (float)(4 * g + 0) * (20.0f / 15.0f) * 0.8f; r.x = __expf(-(u * u));
            u = a - (float)(4 * g + 1) * (20.0f / 15.0f) * 0.8f; r.y = __expf(-(u * u));
            u = a - (float)(4 * g + 2) * (20.0f / 15.0f) * 0.8f; r.z = __expf(-(u * u));
            u = a - (float)(4 * g + 3) * (20.0f / 15.0f) * 0.8f; r.w = __expf(-(u * u));
            *reinterpret_cast<float4*>(o + 4 * g) = r;
        }
    } else {
        int t2 = (blockIdx.x - RBF_BLOCKS) * 256 + threadIdx.x;  // < NE*16 exactly
        int e = t2 >> 4;
        int m = t2 & 15;
        int dst, src;
        load_idx(ei, sel, e, dst, src);
        float d = (float)(dst - src);
        // freq[q] = exp(-q * ln(10000)/8), q = m & 7
        float fr = __expf(-(float)(m & 7) * 1.1512925464970229f);
        float ang = d * fr;
        float s, c;
        sincosf(ang, &s, &c);                     // accurate path: |ang| up to 2e4 rad
        out[(size_t)e * FEAT + 400 + m] = (m < 8) ? c : s;
    }
}

extern "C" void kernel_launch(void* const* d_in, const int* in_sizes, int n_in,
                              void* d_out, int out_size, void* d_ws, size_t ws_size,
                              hipStream_t stream) {
    const float* bb = (const float*)d_in[0];
    const int* ei = (const int*)d_in[1];
    int* flag = (int*)d_ws;
    float* bb5 = (float*)((char*)d_ws + 64);
    float* out = (float*)d_out;

    hipLaunchKernelGGL(prep_kernel, dim3((NN + 255) / 256), dim3(256), 0, stream,
                       bb, ei, flag, bb5);
    hipLaunchKernelGGL(edge_kernel, dim3(RBF_BLOCKS + POS_BLOCKS), dim3(256), 0, stream,
                       ei, bb5, flag, out);
}